// Round 3
// baseline (1187.628 us; speedup 1.0000x reference)
//
#include <hip/hip_runtime.h>

typedef unsigned short u16;
typedef __bf16 bf16x8 __attribute__((ext_vector_type(8)));
typedef float f32x4 __attribute__((ext_vector_type(4)));

typedef __attribute__((address_space(1))) const void gvoid_t;
typedef __attribute__((address_space(3))) void svoid_t;

__device__ __forceinline__ float bf2f(u16 u) {
  union { unsigned int i; float f; } v; v.i = ((unsigned int)u) << 16; return v.f;
}
__device__ __forceinline__ u16 f2bf(float f) {
  union { float f; unsigned int i; } v; v.f = f;
  unsigned int u = v.i;
  return (u16)((u + 0x7fffu + ((u >> 16) & 1u)) >> 16);
}
__device__ __forceinline__ void async_copy16(const u16* g, u16* l) {
  __builtin_amdgcn_global_load_lds((gvoid_t*)g, (svoid_t*)l, 16, 0, 0);
}
__device__ __forceinline__ f32x4 mfma16(bf16x8 a, bf16x8 b, f32x4 c) {
  return __builtin_amdgcn_mfma_f32_16x16x32_bf16(a, b, c, 0, 0, 0);
}

// ---------------- fp32 -> bf16 elementwise pack ----------------
__global__ __launch_bounds__(256) void pack_bf16(const float* __restrict__ src, u16* __restrict__ dst, int n4) {
  int i = blockIdx.x * 256 + threadIdx.x;
  if (i >= n4) return;
  float4 v = *(const float4*)(src + (size_t)i * 4);
  ushort4 o;
  o.x = f2bf(v.x); o.y = f2bf(v.y); o.z = f2bf(v.z); o.w = f2bf(v.w);
  *(ushort4*)(dst + (size_t)i * 4) = o;
}

// ---------------- fp32 transpose+cast: src[R][C] f32 -> dst[C][R] bf16 ----------------
__global__ void transpose_f2b(const float* __restrict__ src, u16* __restrict__ dst, int R, int C) {
  __shared__ u16 t[32][33];
  const int c0 = blockIdx.x * 32, r0 = blockIdx.y * 32;
  const int tx = threadIdx.x, ty = threadIdx.y;
#pragma unroll
  for (int i = 0; i < 4; ++i) {
    int r = r0 + ty + i * 8;
    t[ty + i * 8][tx] = f2bf(src[(size_t)r * C + c0 + tx]);
  }
  __syncthreads();
#pragma unroll
  for (int i = 0; i < 4; ++i) {
    int c = c0 + ty + i * 8;
    dst[(size_t)c * R + r0 + tx] = t[tx][ty + i * 8];
  }
}

// ---------------- V transpose: qkv v-part (bf16) -> vT[bh][64][2048] ----------------
__global__ void transpose_v(const u16* __restrict__ qkv, u16* __restrict__ vT) {
  __shared__ u16 t[32][33];
  const int bh = blockIdx.z;
  const int b = bh >> 4, h = bh & 15;
  const int l0 = blockIdx.x * 32, d0 = blockIdx.y * 32;
  const int tx = threadIdx.x, ty = threadIdx.y;
#pragma unroll
  for (int i = 0; i < 4; ++i) {
    int l = l0 + ty + i * 8;
    t[ty + i * 8][tx] = qkv[(size_t)(b * 2048 + l) * 3072 + 2048 + h * 64 + d0 + tx];
  }
  __syncthreads();
#pragma unroll
  for (int i = 0; i < 4; ++i) {
    int d = d0 + ty + i * 8;
    vT[((size_t)bh * 64 + d) * 2048 + l0 + tx] = t[tx][ty + i * 8];
  }
}

// ---------------- m97-style GEMM: C[M,N](bf16) = A[M,K](bf16) @ Bt[N,K]^T (+bias f32)(+gelu) ----------------
// EPI: 0 = none, 1 = +bias, 2 = +bias+gelu(exact)
template <int EPI>
__global__ __launch_bounds__(256) void gemm_bt(const u16* __restrict__ A, const u16* __restrict__ Bt,
                                               const float* __restrict__ bias, u16* __restrict__ C,
                                               int M, int N, int K) {
  __shared__ __align__(16) u16 As[128 * 32];
  __shared__ __align__(16) u16 Bs[128 * 32];
  const int tid = threadIdx.x;
  const int wave = tid >> 6, lane = tid & 63;
  const int quad = lane >> 4, l16 = lane & 15;
  const int wm = wave >> 1, wn = wave & 1;
  const int m0 = blockIdx.y * 128, n0 = blockIdx.x * 128;
  const int srow = lane >> 2, scol = (lane & 3) * 8;
  f32x4 acc[4][4] = {};
  for (int k0 = 0; k0 < K; k0 += 32) {
#pragma unroll
    for (int rr = 0; rr < 2; ++rr) {
      const int chunk = rr * 4 + wave;
      const int row = chunk * 16 + srow;
      async_copy16(&A[(size_t)(m0 + row) * K + k0 + scol], &As[chunk * 16 * 32]);
      async_copy16(&Bt[(size_t)(n0 + row) * K + k0 + scol], &Bs[chunk * 16 * 32]);
    }
    __syncthreads();
    bf16x8 af[4], bfv[4];
#pragma unroll
    for (int i = 0; i < 4; ++i)
      af[i] = *(const bf16x8*)&As[(wm * 64 + i * 16 + l16) * 32 + quad * 8];
#pragma unroll
    for (int j = 0; j < 4; ++j)
      bfv[j] = *(const bf16x8*)&Bs[(wn * 64 + j * 16 + l16) * 32 + quad * 8];
#pragma unroll
    for (int i = 0; i < 4; ++i)
#pragma unroll
      for (int j = 0; j < 4; ++j)
        acc[i][j] = mfma16(af[i], bfv[j], acc[i][j]);
    __syncthreads();
  }
#pragma unroll
  for (int i = 0; i < 4; ++i)
#pragma unroll
    for (int j = 0; j < 4; ++j) {
      const int col = n0 + wn * 64 + j * 16 + l16;
      float bv = 0.f;
      if (EPI > 0) bv = bias[col];
#pragma unroll
      for (int r = 0; r < 4; ++r) {
        const int row = m0 + wm * 64 + i * 16 + quad * 4 + r;
        float v = acc[i][j][r] + bv;
        if (EPI == 2) v = 0.5f * v * (1.f + erff(v * 0.70710678118654752f));
        C[(size_t)row * N + col] = f2bf(v);
      }
    }
}

// ---------------- flash attention: one wave = one 16-row Q tile, 32-key K/V tiles ----------------
__global__ __launch_bounds__(256) void attn_kernel(const u16* __restrict__ qkv, const u16* __restrict__ vT,
                                                   const float* __restrict__ btab, u16* __restrict__ ctx) {
  const int wave = threadIdx.x >> 6, lane = threadIdx.x & 63;
  const int quad = lane >> 4, l16 = lane & 15;
  const int bh = blockIdx.x >> 5;                 // 0..63
  const int qt = (blockIdx.x & 31) * 4 + wave;    // 0..127
  const int b = bh >> 4, h = bh & 15;
  const int q0 = qt * 16;
  const float scale = 0.125f;  // 64^-0.5

  // Q A-frags: A[m=l16][k=quad*8+j], k-chunks 0..31 / 32..63
  bf16x8 qf[2];
  {
    size_t base = ((size_t)(b * 2048) + q0 + l16) * 3072 + h * 64 + quad * 8;
    qf[0] = *(const bf16x8*)&qkv[base];
    qf[1] = *(const bf16x8*)&qkv[base + 32];
  }

  float m_i[4], l_i[4];
  f32x4 o[4] = {};
#pragma unroll
  for (int r = 0; r < 4; ++r) { m_i[r] = -1e30f; l_i[r] = 0.f; }

  // per-wave P tile, 16 rows x 32 keys
  __shared__ __align__(16) u16 Pt[4][16 * 32];
  u16* pw = Pt[wave];

  for (int kt = 0; kt < 64; ++kt) {
    const int kbase = kt * 32;
    // QK^T for two 16-key sub-tiles; C layout: row=quad*4+r (query), col=l16 (key)
    f32x4 s[2];
#pragma unroll
    for (int t = 0; t < 2; ++t) {
      size_t krow = ((size_t)(b * 2048) + kbase + t * 16 + l16) * 3072 + 1024 + h * 64 + quad * 8;
      bf16x8 kf0 = *(const bf16x8*)&qkv[krow];
      bf16x8 kf1 = *(const bf16x8*)&qkv[krow + 32];
      f32x4 z = {0.f, 0.f, 0.f, 0.f};
      z = mfma16(qf[0], kf0, z);
      z = mfma16(qf[1], kf1, z);
      s[t] = z;
    }
    float sv[2][4];
#pragma unroll
    for (int t = 0; t < 2; ++t)
#pragma unroll
      for (int r = 0; r < 4; ++r) {
        int j = kbase + t * 16 + l16;
        int i = q0 + quad * 4 + r;
        int rel = j - i + 511;
        rel = min(max(rel, 0), 1022);
        sv[t][r] = s[t][r] * scale + btab[rel * 16 + h];
      }
    float mx[4];
#pragma unroll
    for (int r = 0; r < 4; ++r) mx[r] = fmaxf(sv[0][r], sv[1][r]);
#pragma unroll
    for (int off = 1; off < 16; off <<= 1)
#pragma unroll
      for (int r = 0; r < 4; ++r) mx[r] = fmaxf(mx[r], __shfl_xor(mx[r], off));
    float p[2][4], al[4], psum[4];
#pragma unroll
    for (int r = 0; r < 4; ++r) {
      float mn = fmaxf(m_i[r], mx[r]);
      al[r] = __expf(m_i[r] - mn);
      m_i[r] = mn;
      p[0][r] = __expf(sv[0][r] - mn);
      p[1][r] = __expf(sv[1][r] - mn);
      psum[r] = p[0][r] + p[1][r];
    }
#pragma unroll
    for (int off = 1; off < 16; off <<= 1)
#pragma unroll
      for (int r = 0; r < 4; ++r) psum[r] += __shfl_xor(psum[r], off);
#pragma unroll
    for (int r = 0; r < 4; ++r) l_i[r] = l_i[r] * al[r] + psum[r];
    // P: C-layout -> A-layout (16x32) via per-wave LDS round trip
#pragma unroll
    for (int t = 0; t < 2; ++t)
#pragma unroll
      for (int r = 0; r < 4; ++r) pw[(quad * 4 + r) * 32 + t * 16 + l16] = f2bf(p[t][r]);
    __asm volatile("s_waitcnt lgkmcnt(0)" ::: "memory");
    bf16x8 pa = *(const bf16x8*)&pw[l16 * 32 + quad * 8];
    __asm volatile("s_waitcnt lgkmcnt(0)" ::: "memory");
    // PV over K=32 keys: B[k=quad*8+j][n=l16], vT contiguous in key
#pragma unroll
    for (int c = 0; c < 4; ++c) {
      bf16x8 vf = *(const bf16x8*)&vT[((size_t)bh * 64 + c * 16 + l16) * 2048 + kbase + quad * 8];
      f32x4 oc = o[c];
#pragma unroll
      for (int r = 0; r < 4; ++r) oc[r] *= al[r];
      o[c] = mfma16(pa, vf, oc);
    }
  }
#pragma unroll
  for (int c = 0; c < 4; ++c)
#pragma unroll
    for (int r = 0; r < 4; ++r) {
      float v = o[c][r] / l_i[r];
      ctx[((size_t)(b * 2048 + q0 + quad * 4 + r)) * 1024 + h * 64 + c * 16 + l16] = f2bf(v);
    }
}

// ---------------- residual add + LayerNorm over D=1024 ----------------
// A_F32: a-operand fp32 (else bf16); O_F32: output fp32 (else bf16). b is always bf16.
template <int A_F32, int O_F32>
__global__ __launch_bounds__(256) void add_ln(const void* __restrict__ av, const u16* __restrict__ b,
                                              const float* __restrict__ gamma, const float* __restrict__ beta,
                                              void* __restrict__ ov) {
  const int row = blockIdx.x, t = threadIdx.x;
  const size_t base = (size_t)row * 1024 + t * 4;
  float x0, x1, x2, x3;
  if (A_F32) {
    float4 a4 = *(const float4*)((const float*)av + base);
    x0 = a4.x; x1 = a4.y; x2 = a4.z; x3 = a4.w;
  } else {
    ushort4 a4 = *(const ushort4*)((const u16*)av + base);
    x0 = bf2f(a4.x); x1 = bf2f(a4.y); x2 = bf2f(a4.z); x3 = bf2f(a4.w);
  }
  ushort4 b4 = *(const ushort4*)&b[base];
  x0 += bf2f(b4.x); x1 += bf2f(b4.y); x2 += bf2f(b4.z); x3 += bf2f(b4.w);
  float s = x0 + x1 + x2 + x3;
  float q = x0 * x0 + x1 * x1 + x2 * x2 + x3 * x3;
  for (int off = 32; off > 0; off >>= 1) { s += __shfl_down(s, off); q += __shfl_down(q, off); }
  __shared__ float sh_s[4], sh_q[4];
  if ((t & 63) == 0) { sh_s[t >> 6] = s; sh_q[t >> 6] = q; }
  __syncthreads();
  s = sh_s[0] + sh_s[1] + sh_s[2] + sh_s[3];
  q = sh_q[0] + sh_q[1] + sh_q[2] + sh_q[3];
  float mu = s * (1.f / 1024.f);
  float var = q * (1.f / 1024.f) - mu * mu;
  float rs = rsqrtf(var + 1e-5f);
  float4 g4 = *(const float4*)&gamma[t * 4];
  float4 be4 = *(const float4*)&beta[t * 4];
  float y0 = (x0 - mu) * rs * g4.x + be4.x;
  float y1 = (x1 - mu) * rs * g4.y + be4.y;
  float y2 = (x2 - mu) * rs * g4.z + be4.z;
  float y3 = (x3 - mu) * rs * g4.w + be4.w;
  if (O_F32) {
    float4 o4 = {y0, y1, y2, y3};
    *(float4*)((float*)ov + base) = o4;
  } else {
    ushort4 o4;
    o4.x = f2bf(y0); o4.y = f2bf(y1); o4.z = f2bf(y2); o4.w = f2bf(y3);
    *(ushort4*)((u16*)ov + base) = o4;
  }
}

extern "C" void kernel_launch(void* const* d_in, const int* in_sizes, int n_in,
                              void* d_out, int out_size, void* d_ws, size_t ws_size,
                              hipStream_t stream) {
  const float* x      = (const float*)d_in[0];
  const float* w_qkv  = (const float*)d_in[1];
  const float* w_out  = (const float*)d_in[2];
  const float* b_out  = (const float*)d_in[3];
  const float* btab   = (const float*)d_in[4];
  const float* gamma1 = (const float*)d_in[5];
  const float* beta1  = (const float*)d_in[6];
  const float* w_ff1  = (const float*)d_in[7];
  const float* b_ff1  = (const float*)d_in[8];
  const float* w_ff2  = (const float*)d_in[9];
  const float* b_ff2  = (const float*)d_in[10];
  const float* gamma2 = (const float*)d_in[11];
  const float* beta2  = (const float*)d_in[12];
  float* out = (float*)d_out;

  char* w = (char*)d_ws;
  auto alloc = [&](size_t elems) { u16* p = (u16*)w; w += elems * 2; return p; };
  u16* wqkvT = alloc(3072UL * 1024);
  u16* woutT = alloc(1024UL * 1024);
  u16* wff1T = alloc(4096UL * 1024);
  u16* wff2T = alloc(1024UL * 4096);
  u16* xb    = alloc(8192UL * 1024);   // x cast to bf16
  u16* qkv   = alloc(8192UL * 3072);   // dead after attn
  u16* vT    = alloc(64UL * 64 * 2048);// dead after attn
  u16* ctx   = alloc(8192UL * 1024);   // dead after w_out gemm
  u16* x1    = alloc(8192UL * 1024);
  u16* attn  = qkv;                    // attn-out: qkv region dead by then
  u16* h     = qkv;                    // h (33.5M elems) spans qkv+vT (33.5M), both dead
  u16* ffn   = ctx;                    // ctx dead after w_out gemm

  dim3 tb(32, 8);
  pack_bf16<<<8192, 256, 0, stream>>>(x, xb, 8192 * 1024 / 4);
  transpose_f2b<<<dim3(3072 / 32, 1024 / 32), tb, 0, stream>>>(w_qkv, wqkvT, 1024, 3072);
  transpose_f2b<<<dim3(1024 / 32, 1024 / 32), tb, 0, stream>>>(w_out, woutT, 1024, 1024);
  transpose_f2b<<<dim3(4096 / 32, 1024 / 32), tb, 0, stream>>>(w_ff1, wff1T, 1024, 4096);
  transpose_f2b<<<dim3(1024 / 32, 4096 / 32), tb, 0, stream>>>(w_ff2, wff2T, 4096, 1024);

  gemm_bt<0><<<dim3(24, 64), 256, 0, stream>>>(xb, wqkvT, nullptr, qkv, 8192, 3072, 1024);
  transpose_v<<<dim3(64, 2, 64), tb, 0, stream>>>(qkv, vT);
  attn_kernel<<<2048, 256, 0, stream>>>(qkv, vT, btab, ctx);
  gemm_bt<1><<<dim3(8, 64), 256, 0, stream>>>(ctx, woutT, b_out, attn, 8192, 1024, 1024);
  add_ln<1, 0><<<8192, 256, 0, stream>>>(x, attn, gamma1, beta1, x1);
  gemm_bt<2><<<dim3(32, 64), 256, 0, stream>>>(x1, wff1T, b_ff1, h, 8192, 4096, 1024);
  gemm_bt<1><<<dim3(8, 64), 256, 0, stream>>>(h, wff2T, b_ff2, ffn, 8192, 1024, 4096);
  add_ln<0, 1><<<8192, 256, 0, stream>>>(x1, ffn, gamma2, beta2, out);
}

// Round 4
// 640.620 us; speedup vs baseline: 1.8539x; 1.8539x over previous
//
#include <hip/hip_runtime.h>

typedef unsigned short u16;
typedef __bf16 bf16x8 __attribute__((ext_vector_type(8)));
typedef float f32x4 __attribute__((ext_vector_type(4)));
typedef unsigned short u16x8 __attribute__((ext_vector_type(8)));

typedef __attribute__((address_space(1))) const void gvoid_t;
typedef __attribute__((address_space(3))) void svoid_t;

__device__ __forceinline__ float bf2f(u16 u) {
  union { unsigned int i; float f; } v; v.i = ((unsigned int)u) << 16; return v.f;
}
__device__ __forceinline__ u16 f2bf(float f) {
  union { float f; unsigned int i; } v; v.f = f;
  unsigned int u = v.i;
  return (u16)((u + 0x7fffu + ((u >> 16) & 1u)) >> 16);
}
__device__ __forceinline__ void async_copy16(const u16* g, u16* l) {
  __builtin_amdgcn_global_load_lds((gvoid_t*)g, (svoid_t*)l, 16, 0, 0);
}
__device__ __forceinline__ f32x4 mfma16(bf16x8 a, bf16x8 b, f32x4 c) {
  return __builtin_amdgcn_mfma_f32_16x16x32_bf16(a, b, c, 0, 0, 0);
}

// ---------------- fp32 -> bf16 elementwise pack ----------------
__global__ __launch_bounds__(256) void pack_bf16(const float* __restrict__ src, u16* __restrict__ dst, int n4) {
  int i = blockIdx.x * 256 + threadIdx.x;
  if (i >= n4) return;
  float4 v = *(const float4*)(src + (size_t)i * 4);
  ushort4 o;
  o.x = f2bf(v.x); o.y = f2bf(v.y); o.z = f2bf(v.z); o.w = f2bf(v.w);
  *(ushort4*)(dst + (size_t)i * 4) = o;
}

// ---------------- fp32 transpose+cast: src[R][C] f32 -> dst[C][R] bf16 ----------------
__global__ void transpose_f2b(const float* __restrict__ src, u16* __restrict__ dst, int R, int C) {
  __shared__ u16 t[32][33];
  const int c0 = blockIdx.x * 32, r0 = blockIdx.y * 32;
  const int tx = threadIdx.x, ty = threadIdx.y;
#pragma unroll
  for (int i = 0; i < 4; ++i) {
    int r = r0 + ty + i * 8;
    t[ty + i * 8][tx] = f2bf(src[(size_t)r * C + c0 + tx]);
  }
  __syncthreads();
#pragma unroll
  for (int i = 0; i < 4; ++i) {
    int c = c0 + ty + i * 8;
    dst[(size_t)c * R + r0 + tx] = t[tx][ty + i * 8];
  }
}

// ---------------- V transpose: qkv v-part (bf16) -> vT2[bh][kt][d][32] (key-tiled) ----------------
__global__ void transpose_v(const u16* __restrict__ qkv, u16* __restrict__ vT2) {
  __shared__ u16 t[32][33];
  const int bh = blockIdx.z;
  const int b = bh >> 4, h = bh & 15;
  const int l0 = blockIdx.x * 32, d0 = blockIdx.y * 32;
  const int tx = threadIdx.x, ty = threadIdx.y;
#pragma unroll
  for (int i = 0; i < 4; ++i) {
    int l = l0 + ty + i * 8;
    t[ty + i * 8][tx] = qkv[(size_t)(b * 2048 + l) * 3072 + 2048 + h * 64 + d0 + tx];
  }
  __syncthreads();
#pragma unroll
  for (int i = 0; i < 4; ++i) {
    int d = d0 + ty + i * 8;
    // tiled layout: [bh][key/32][d][key%32]
    vT2[(size_t)bh * 131072 + (l0 >> 5) * 2048 + d * 32 + tx] = t[tx][ty + i * 8];
  }
}

// ---------------- m97-style GEMM: C[M,N](bf16) = A[M,K](bf16) @ Bt[N,K]^T (+bias f32)(+gelu) ----------------
template <int EPI>
__global__ __launch_bounds__(256) void gemm_bt(const u16* __restrict__ A, const u16* __restrict__ Bt,
                                               const float* __restrict__ bias, u16* __restrict__ C,
                                               int M, int N, int K) {
  __shared__ __align__(16) u16 As[128 * 32];
  __shared__ __align__(16) u16 Bs[128 * 32];
  const int tid = threadIdx.x;
  const int wave = tid >> 6, lane = tid & 63;
  const int quad = lane >> 4, l16 = lane & 15;
  const int wm = wave >> 1, wn = wave & 1;
  const int m0 = blockIdx.y * 128, n0 = blockIdx.x * 128;
  const int srow = lane >> 2, scol = (lane & 3) * 8;
  f32x4 acc[4][4] = {};
  for (int k0 = 0; k0 < K; k0 += 32) {
#pragma unroll
    for (int rr = 0; rr < 2; ++rr) {
      const int chunk = rr * 4 + wave;
      const int row = chunk * 16 + srow;
      async_copy16(&A[(size_t)(m0 + row) * K + k0 + scol], &As[chunk * 16 * 32]);
      async_copy16(&Bt[(size_t)(n0 + row) * K + k0 + scol], &Bs[chunk * 16 * 32]);
    }
    __syncthreads();
    bf16x8 af[4], bfv[4];
#pragma unroll
    for (int i = 0; i < 4; ++i)
      af[i] = *(const bf16x8*)&As[(wm * 64 + i * 16 + l16) * 32 + quad * 8];
#pragma unroll
    for (int j = 0; j < 4; ++j)
      bfv[j] = *(const bf16x8*)&Bs[(wn * 64 + j * 16 + l16) * 32 + quad * 8];
#pragma unroll
    for (int i = 0; i < 4; ++i)
#pragma unroll
      for (int j = 0; j < 4; ++j)
        acc[i][j] = mfma16(af[i], bfv[j], acc[i][j]);
    __syncthreads();
  }
#pragma unroll
  for (int i = 0; i < 4; ++i)
#pragma unroll
    for (int j = 0; j < 4; ++j) {
      const int col = n0 + wn * 64 + j * 16 + l16;
      float bv = 0.f;
      if (EPI > 0) bv = bias[col];
#pragma unroll
      for (int r = 0; r < 4; ++r) {
        const int row = m0 + wm * 64 + i * 16 + quad * 4 + r;
        float v = acc[i][j][r] + bv;
        if (EPI == 2) v = 0.5f * v * (1.f + erff(v * 0.70710678118654752f));
        C[(size_t)row * N + col] = f2bf(v);
      }
    }
}

// ---------------- flash attention, block-cooperative ----------------
// Block = one (b,h) x 128 q-rows. 4 waves; wave handles 2 q-tiles of 16 rows.
// K/V tiles staged in LDS (coalesced); no-max softmax (scores bounded ~|4|);
// row-sum deferred to epilogue; rel-bias via per-block LDS window.
__global__ __launch_bounds__(256) void attn_kernel(const u16* __restrict__ qkv, const u16* __restrict__ vT2,
                                                   const float* __restrict__ btab, u16* __restrict__ ctx) {
  const int tid = threadIdx.x;
  const int wave = tid >> 6, lane = tid & 63;
  const int quad = lane >> 4, l16 = lane & 15;
  const int bh = blockIdx.x >> 4, qb = blockIdx.x & 15;
  const int b = bh >> 4, h = bh & 15;
  const int q0b = qb * 128;
  const int qw = q0b + wave * 32;  // wave's first q row

  __shared__ __align__(16) u16 Ks[32 * 68];      // [key][64d + 4 pad]
  __shared__ __align__(16) u16 Vs[64 * 36];      // [d][32key + 4 pad]
  __shared__ __align__(16) float bias_s[160];
  __shared__ __align__(16) u16 P[4][2][16 * 36]; // per-wave, per-qtile [row][32key + 4 pad]

  // Q A-frags, pre-scaled by 1/8 (exact in bf16)
  bf16x8 qf[2][2];
#pragma unroll
  for (int qi = 0; qi < 2; ++qi)
#pragma unroll
    for (int kk = 0; kk < 2; ++kk) {
      const u16* qp = &qkv[((size_t)(b * 2048) + qw + qi * 16 + l16) * 3072 + h * 64 + kk * 32 + quad * 8];
      union { u16 s[8]; bf16x8 v; } u;
#pragma unroll
      for (int j = 0; j < 8; ++j) u.s[j] = f2bf(bf2f(qp[j]) * 0.125f);
      qf[qi][kk] = u.v;
    }

  f32x4 o[2][4] = {};
  float psum[2][4] = {};

  const float c_lo = btab[h], c_hi = btab[1022 * 16 + h];
  const int skey = tid >> 3, schunk = tid & 7;  // K staging
  const int svd = tid >> 2, svc = tid & 3;      // V staging

  for (int kt = 0; kt < 64; ++kt) {
    const int kbase = kt * 32;
    const int dmax = kbase - q0b + 31, dmin = kbase - q0b - 127;
    const int mode = (dmax <= -511) ? 1 : (dmin >= 511 ? 2 : 0);
    // ---- stage K, V (coalesced), bias window ----
    {
      u16x8 kv = *(const u16x8*)&qkv[((size_t)(b * 2048) + kbase + skey) * 3072 + 1024 + h * 64 + schunk * 8];
      *(u16x8*)&Ks[skey * 68 + schunk * 8] = kv;
      u16x8 vv = *(const u16x8*)&vT2[(size_t)bh * 131072 + kt * 2048 + tid * 8];
      *(u16x8*)&Vs[svd * 36 + svc * 8] = vv;
    }
    if (mode == 0 && tid < 160) {
      int d = dmin + tid + 511;
      d = min(max(d, 0), 1022);
      bias_s[tid] = btab[d * 16 + h];
    }
    __syncthreads();
    // ---- QK^T + exp ----
    bf16x8 kf0[2], kf1[2];
#pragma unroll
    for (int t = 0; t < 2; ++t) {
      kf0[t] = *(const bf16x8*)&Ks[(t * 16 + l16) * 68 + quad * 8];
      kf1[t] = *(const bf16x8*)&Ks[(t * 16 + l16) * 68 + 32 + quad * 8];
    }
#pragma unroll
    for (int qi = 0; qi < 2; ++qi) {
      u16* pw = P[wave][qi];
#pragma unroll
      for (int t = 0; t < 2; ++t) {
        f32x4 z = {0.f, 0.f, 0.f, 0.f};
        z = mfma16(qf[qi][0], kf0[t], z);
        z = mfma16(qf[qi][1], kf1[t], z);
#pragma unroll
        for (int r = 0; r < 4; ++r) {
          float bv;
          if (mode == 1) bv = c_lo;
          else if (mode == 2) bv = c_hi;
          else bv = bias_s[t * 16 + l16 - (wave * 32 + qi * 16 + quad * 4 + r) + 127];
          float p = __expf(z[r] + bv);
          psum[qi][r] += p;
          union { float f; unsigned int i; } cv; cv.f = p;
          pw[(quad * 4 + r) * 36 + t * 16 + l16] = (u16)(cv.i >> 16);
        }
      }
    }
    // ---- PV ----
    bf16x8 pa0 = *(const bf16x8*)&P[wave][0][l16 * 36 + quad * 8];
    bf16x8 pa1 = *(const bf16x8*)&P[wave][1][l16 * 36 + quad * 8];
#pragma unroll
    for (int c = 0; c < 4; ++c) {
      bf16x8 vf = *(const bf16x8*)&Vs[(c * 16 + l16) * 36 + quad * 8];
      o[0][c] = mfma16(pa0, vf, o[0][c]);
      o[1][c] = mfma16(pa1, vf, o[1][c]);
    }
    __syncthreads();
  }
  // ---- epilogue: row sums + normalize ----
#pragma unroll
  for (int qi = 0; qi < 2; ++qi)
#pragma unroll
    for (int off = 1; off < 16; off <<= 1)
#pragma unroll
      for (int r = 0; r < 4; ++r) psum[qi][r] += __shfl_xor(psum[qi][r], off);
#pragma unroll
  for (int qi = 0; qi < 2; ++qi)
#pragma unroll
    for (int r = 0; r < 4; ++r) {
      float inv = 1.f / psum[qi][r];
      int row = qw + qi * 16 + quad * 4 + r;
#pragma unroll
      for (int c = 0; c < 4; ++c)
        ctx[((size_t)(b * 2048 + row)) * 1024 + h * 64 + c * 16 + l16] = f2bf(o[qi][c][r] * inv);
    }
}

// ---------------- residual add + LayerNorm over D=1024 ----------------
template <int A_F32, int O_F32>
__global__ __launch_bounds__(256) void add_ln(const void* __restrict__ av, const u16* __restrict__ b,
                                              const float* __restrict__ gamma, const float* __restrict__ beta,
                                              void* __restrict__ ov) {
  const int row = blockIdx.x, t = threadIdx.x;
  const size_t base = (size_t)row * 1024 + t * 4;
  float x0, x1, x2, x3;
  if (A_F32) {
    float4 a4 = *(const float4*)((const float*)av + base);
    x0 = a4.x; x1 = a4.y; x2 = a4.z; x3 = a4.w;
  } else {
    ushort4 a4 = *(const ushort4*)((const u16*)av + base);
    x0 = bf2f(a4.x); x1 = bf2f(a4.y); x2 = bf2f(a4.z); x3 = bf2f(a4.w);
  }
  ushort4 b4 = *(const ushort4*)&b[base];
  x0 += bf2f(b4.x); x1 += bf2f(b4.y); x2 += bf2f(b4.z); x3 += bf2f(b4.w);
  float s = x0 + x1 + x2 + x3;
  float q = x0 * x0 + x1 * x1 + x2 * x2 + x3 * x3;
  for (int off = 32; off > 0; off >>= 1) { s += __shfl_down(s, off); q += __shfl_down(q, off); }
  __shared__ float sh_s[4], sh_q[4];
  if ((t & 63) == 0) { sh_s[t >> 6] = s; sh_q[t >> 6] = q; }
  __syncthreads();
  s = sh_s[0] + sh_s[1] + sh_s[2] + sh_s[3];
  q = sh_q[0] + sh_q[1] + sh_q[2] + sh_q[3];
  float mu = s * (1.f / 1024.f);
  float var = q * (1.f / 1024.f) - mu * mu;
  float rs = rsqrtf(var + 1e-5f);
  float4 g4 = *(const float4*)&gamma[t * 4];
  float4 be4 = *(const float4*)&beta[t * 4];
  float y0 = (x0 - mu) * rs * g4.x + be4.x;
  float y1 = (x1 - mu) * rs * g4.y + be4.y;
  float y2 = (x2 - mu) * rs * g4.z + be4.z;
  float y3 = (x3 - mu) * rs * g4.w + be4.w;
  if (O_F32) {
    float4 o4 = {y0, y1, y2, y3};
    *(float4*)((float*)ov + base) = o4;
  } else {
    ushort4 o4;
    o4.x = f2bf(y0); o4.y = f2bf(y1); o4.z = f2bf(y2); o4.w = f2bf(y3);
    *(ushort4*)((u16*)ov + base) = o4;
  }
}

extern "C" void kernel_launch(void* const* d_in, const int* in_sizes, int n_in,
                              void* d_out, int out_size, void* d_ws, size_t ws_size,
                              hipStream_t stream) {
  const float* x      = (const float*)d_in[0];
  const float* w_qkv  = (const float*)d_in[1];
  const float* w_out  = (const float*)d_in[2];
  const float* b_out  = (const float*)d_in[3];
  const float* btab   = (const float*)d_in[4];
  const float* gamma1 = (const float*)d_in[5];
  const float* beta1  = (const float*)d_in[6];
  const float* w_ff1  = (const float*)d_in[7];
  const float* b_ff1  = (const float*)d_in[8];
  const float* w_ff2  = (const float*)d_in[9];
  const float* b_ff2  = (const float*)d_in[10];
  const float* gamma2 = (const float*)d_in[11];
  const float* beta2  = (const float*)d_in[12];
  float* out = (float*)d_out;

  char* w = (char*)d_ws;
  auto alloc = [&](size_t elems) { u16* p = (u16*)w; w += elems * 2; return p; };
  u16* wqkvT = alloc(3072UL * 1024);
  u16* woutT = alloc(1024UL * 1024);
  u16* wff1T = alloc(4096UL * 1024);
  u16* wff2T = alloc(1024UL * 4096);
  u16* xb    = alloc(8192UL * 1024);   // x cast to bf16
  u16* qkv   = alloc(8192UL * 3072);   // dead after attn
  u16* vT2   = alloc(64UL * 64 * 2048);// dead after attn
  u16* ctx   = alloc(8192UL * 1024);   // dead after w_out gemm
  u16* x1    = alloc(8192UL * 1024);
  u16* attn  = qkv;                    // qkv region dead by then
  u16* h     = qkv;                    // h spans qkv+vT2, both dead
  u16* ffn   = ctx;                    // ctx dead after w_out gemm

  dim3 tb(32, 8);
  pack_bf16<<<8192, 256, 0, stream>>>(x, xb, 8192 * 1024 / 4);
  transpose_f2b<<<dim3(3072 / 32, 1024 / 32), tb, 0, stream>>>(w_qkv, wqkvT, 1024, 3072);
  transpose_f2b<<<dim3(1024 / 32, 1024 / 32), tb, 0, stream>>>(w_out, woutT, 1024, 1024);
  transpose_f2b<<<dim3(4096 / 32, 1024 / 32), tb, 0, stream>>>(w_ff1, wff1T, 1024, 4096);
  transpose_f2b<<<dim3(1024 / 32, 4096 / 32), tb, 0, stream>>>(w_ff2, wff2T, 4096, 1024);

  gemm_bt<0><<<dim3(24, 64), 256, 0, stream>>>(xb, wqkvT, nullptr, qkv, 8192, 3072, 1024);
  transpose_v<<<dim3(64, 2, 64), tb, 0, stream>>>(qkv, vT2);
  attn_kernel<<<1024, 256, 0, stream>>>(qkv, vT2, btab, ctx);
  gemm_bt<1><<<dim3(8, 64), 256, 0, stream>>>(ctx, woutT, b_out, attn, 8192, 1024, 1024);
  add_ln<1, 0><<<8192, 256, 0, stream>>>(x, attn, gamma1, beta1, x1);
  gemm_bt<2><<<dim3(32, 64), 256, 0, stream>>>(x1, wff1T, b_ff1, h, 8192, 4096, 1024);
  gemm_bt<1><<<dim3(8, 64), 256, 0, stream>>>(h, wff2T, b_ff2, ffn, 8192, 1024, 4096);
  add_ln<0, 1><<<8192, 256, 0, stream>>>(x1, ffn, gamma2, beta2, out);
}

// Round 5
// 608.468 us; speedup vs baseline: 1.9518x; 1.0528x over previous
//
#include <hip/hip_runtime.h>

typedef unsigned short u16;
typedef __bf16 bf16x8 __attribute__((ext_vector_type(8)));
typedef float f32x4 __attribute__((ext_vector_type(4)));
typedef unsigned short u16x8 __attribute__((ext_vector_type(8)));

typedef __attribute__((address_space(1))) const void gvoid_t;
typedef __attribute__((address_space(3))) void svoid_t;

__device__ __forceinline__ float bf2f(u16 u) {
  union { unsigned int i; float f; } v; v.i = ((unsigned int)u) << 16; return v.f;
}
__device__ __forceinline__ u16 f2bf(float f) {
  union { float f; unsigned int i; } v; v.f = f;
  unsigned int u = v.i;
  return (u16)((u + 0x7fffu + ((u >> 16) & 1u)) >> 16);
}
__device__ __forceinline__ void async_copy16(const u16* g, u16* l) {
  __builtin_amdgcn_global_load_lds((gvoid_t*)g, (svoid_t*)l, 16, 0, 0);
}
__device__ __forceinline__ f32x4 mfma16(bf16x8 a, bf16x8 b, f32x4 c) {
  return __builtin_amdgcn_mfma_f32_16x16x32_bf16(a, b, c, 0, 0, 0);
}

// ---------------- fp32 -> bf16 elementwise pack ----------------
__global__ __launch_bounds__(256) void pack_bf16(const float* __restrict__ src, u16* __restrict__ dst, int n4) {
  int i = blockIdx.x * 256 + threadIdx.x;
  if (i >= n4) return;
  float4 v = *(const float4*)(src + (size_t)i * 4);
  ushort4 o;
  o.x = f2bf(v.x); o.y = f2bf(v.y); o.z = f2bf(v.z); o.w = f2bf(v.w);
  *(ushort4*)(dst + (size_t)i * 4) = o;
}

// ---------------- fp32 transpose+cast: src[R][C] f32 -> dst[C][R] bf16 ----------------
__global__ void transpose_f2b(const float* __restrict__ src, u16* __restrict__ dst, int R, int C) {
  __shared__ u16 t[32][33];
  const int c0 = blockIdx.x * 32, r0 = blockIdx.y * 32;
  const int tx = threadIdx.x, ty = threadIdx.y;
#pragma unroll
  for (int i = 0; i < 4; ++i) {
    int r = r0 + ty + i * 8;
    t[ty + i * 8][tx] = f2bf(src[(size_t)r * C + c0 + tx]);
  }
  __syncthreads();
#pragma unroll
  for (int i = 0; i < 4; ++i) {
    int c = c0 + ty + i * 8;
    dst[(size_t)c * R + r0 + tx] = t[tx][ty + i * 8];
  }
}

// ---------------- V transpose: qkv v-part (bf16) -> vT2[bh][kt32][d][32 perm] ----------------
// key position within 32-tile is interleaved: pos = 2*(tx&15) + (tx>>4), matching the
// t-interleaved P layout in attn_kernel.
__global__ void transpose_v(const u16* __restrict__ qkv, u16* __restrict__ vT2) {
  __shared__ u16 t[32][33];
  const int bh = blockIdx.z;
  const int b = bh >> 4, h = bh & 15;
  const int l0 = blockIdx.x * 32, d0 = blockIdx.y * 32;
  const int tx = threadIdx.x, ty = threadIdx.y;
#pragma unroll
  for (int i = 0; i < 4; ++i) {
    int l = l0 + ty + i * 8;
    t[ty + i * 8][tx] = qkv[(size_t)(b * 2048 + l) * 3072 + 2048 + h * 64 + d0 + tx];
  }
  __syncthreads();
  const int pos = 2 * (tx & 15) + (tx >> 4);
#pragma unroll
  for (int i = 0; i < 4; ++i) {
    int d = d0 + ty + i * 8;
    vT2[(size_t)bh * 131072 + (l0 >> 5) * 2048 + d * 32 + pos] = t[tx][ty + i * 8];
  }
}

// ---------------- m97-style GEMM: C[M,N](bf16) = A[M,K](bf16) @ Bt[N,K]^T (+bias f32)(+gelu) ----------------
template <int EPI>
__global__ __launch_bounds__(256) void gemm_bt(const u16* __restrict__ A, const u16* __restrict__ Bt,
                                               const float* __restrict__ bias, u16* __restrict__ C,
                                               int M, int N, int K) {
  __shared__ __align__(16) u16 As[128 * 32];
  __shared__ __align__(16) u16 Bs[128 * 32];
  const int tid = threadIdx.x;
  const int wave = tid >> 6, lane = tid & 63;
  const int quad = lane >> 4, l16 = lane & 15;
  const int wm = wave >> 1, wn = wave & 1;
  const int m0 = blockIdx.y * 128, n0 = blockIdx.x * 128;
  const int srow = lane >> 2, scol = (lane & 3) * 8;
  f32x4 acc[4][4] = {};
  for (int k0 = 0; k0 < K; k0 += 32) {
#pragma unroll
    for (int rr = 0; rr < 2; ++rr) {
      const int chunk = rr * 4 + wave;
      const int row = chunk * 16 + srow;
      async_copy16(&A[(size_t)(m0 + row) * K + k0 + scol], &As[chunk * 16 * 32]);
      async_copy16(&Bt[(size_t)(n0 + row) * K + k0 + scol], &Bs[chunk * 16 * 32]);
    }
    __syncthreads();
    bf16x8 af[4], bfv[4];
#pragma unroll
    for (int i = 0; i < 4; ++i)
      af[i] = *(const bf16x8*)&As[(wm * 64 + i * 16 + l16) * 32 + quad * 8];
#pragma unroll
    for (int j = 0; j < 4; ++j)
      bfv[j] = *(const bf16x8*)&Bs[(wn * 64 + j * 16 + l16) * 32 + quad * 8];
#pragma unroll
    for (int i = 0; i < 4; ++i)
#pragma unroll
      for (int j = 0; j < 4; ++j)
        acc[i][j] = mfma16(af[i], bfv[j], acc[i][j]);
    __syncthreads();
  }
#pragma unroll
  for (int i = 0; i < 4; ++i)
#pragma unroll
    for (int j = 0; j < 4; ++j) {
      const int col = n0 + wn * 64 + j * 16 + l16;
      float bv = 0.f;
      if (EPI > 0) bv = bias[col];
#pragma unroll
      for (int r = 0; r < 4; ++r) {
        const int row = m0 + wm * 64 + i * 16 + quad * 4 + r;
        float v = acc[i][j][r] + bv;
        if (EPI == 2) v = 0.5f * v * (1.f + erff(v * 0.70710678118654752f));
        C[(size_t)row * N + col] = f2bf(v);
      }
    }
}

// ---------------- flash attention, block-cooperative, 64-key iterations ----------------
// Block = one (b,h) x 128 q-rows; wave = 32 q-rows (2 qtiles). No-max softmax in base-2
// (Q pre-scaled by 0.125*log2e, bias *log2e). P stored t-interleaved so two sub-tile
// results pack into one ds_write_b32; V key order permuted to match (transpose_v).
__global__ __launch_bounds__(256, 4) void attn_kernel(const u16* __restrict__ qkv, const u16* __restrict__ vT2,
                                                      const float* __restrict__ btab, u16* __restrict__ ctx) {
  const int tid = threadIdx.x;
  const int wave = tid >> 6, lane = tid & 63;
  const int quad = lane >> 4, l16 = lane & 15;
  const int bh = blockIdx.x >> 4, qb = blockIdx.x & 15;
  const int b = bh >> 4, h = bh & 15;
  const int q0b = qb * 128;
  const int qw = q0b + wave * 32;
  const float LOG2E = 1.4426950408889634f;

  __shared__ __align__(16) u16 Ks[64 * 72];      // [key][64d + 8 pad]   9.2 KB (stride 36 dw: 2-way)
  __shared__ __align__(16) u16 Vs[2][64 * 40];   // [g][d][32perm + 8]  10.2 KB (stride 20 dw: 2-way)
  __shared__ __align__(16) float bias_s[192];    // reversed window, pre-*log2e
  __shared__ __align__(16) u16 P[4][2][16 * 40]; // per-wave per-qtile, reused per g

  // Q A-frags, pre-scaled by 0.125*log2e
  bf16x8 qf[2][2];
#pragma unroll
  for (int qi = 0; qi < 2; ++qi)
#pragma unroll
    for (int kk = 0; kk < 2; ++kk) {
      u16x8 qv = *(const u16x8*)&qkv[((size_t)(b * 2048) + qw + qi * 16 + l16) * 3072 + h * 64 + kk * 32 + quad * 8];
      union { u16 s[8]; bf16x8 v; } u;
#pragma unroll
      for (int j = 0; j < 8; ++j) u.s[j] = f2bf(bf2f(qv[j]) * (0.125f * LOG2E));
      qf[qi][kk] = u.v;
    }

  f32x4 o[2][4] = {};
  float psum[2][4] = {};
  const float c_lo = btab[h] * LOG2E, c_hi = btab[1022 * 16 + h] * LOG2E;
  const int krow = tid >> 2, kc = tid & 3;
  const int rowb0 = wave * 32 + quad * 4;

  for (int kt = 0; kt < 32; ++kt) {
    const int kbase = kt * 64;
    const int dmin = kbase - q0b - 127, dmax = kbase - q0b + 63;
    const int mode = (dmax <= -511) ? 1 : (dmin >= 511 ? 2 : 0);
    // ---- stage K (64x64), V (2 x 64x32perm), bias window ----
#pragma unroll
    for (int half = 0; half < 2; ++half) {
      const int chunk = kc + half * 4;
      u16x8 kv = *(const u16x8*)&qkv[((size_t)(b * 2048) + kbase + krow) * 3072 + 1024 + h * 64 + chunk * 8];
      *(u16x8*)&Ks[krow * 72 + chunk * 8] = kv;
    }
#pragma unroll
    for (int g = 0; g < 2; ++g) {
      u16x8 vv = *(const u16x8*)&vT2[(size_t)bh * 131072 + (2 * kt + g) * 2048 + tid * 8];
      *(u16x8*)&Vs[g][krow * 40 + kc * 8] = vv;
    }
    if (mode == 0 && tid < 192) {
      int idx = dmin + 191 - tid + 511;
      idx = min(max(idx, 0), 1022);
      bias_s[tid] = btab[idx * 16 + h] * LOG2E;
    }
    __syncthreads();
#pragma unroll
    for (int g = 0; g < 2; ++g) {
      // ---- QK^T: two 16-key sub-tiles of this 32-key group ----
      f32x4 z[2][2];
#pragma unroll
      for (int t = 0; t < 2; ++t) {
        const u16* kr = &Ks[(g * 32 + t * 16 + l16) * 72 + quad * 8];
        bf16x8 kf0 = *(const bf16x8*)kr;
        bf16x8 kf1 = *(const bf16x8*)(kr + 32);
#pragma unroll
        for (int qi = 0; qi < 2; ++qi) {
          f32x4 zz = {0.f, 0.f, 0.f, 0.f};
          zz = mfma16(qf[qi][0], kf0, zz);
          zz = mfma16(qf[qi][1], kf1, zz);
          z[t][qi] = zz;
        }
      }
      // ---- bias + exp2 + packed P store ----
#pragma unroll
      for (int qi = 0; qi < 2; ++qi) {
        u16* pw = P[wave][qi];
#pragma unroll
        for (int r = 0; r < 4; ++r) {
          const int rowb = rowb0 + qi * 16 + r;
          float b0, b1;
          if (mode == 1) { b0 = c_lo; b1 = c_lo; }
          else if (mode == 2) { b0 = c_hi; b1 = c_hi; }
          else {
            b0 = bias_s[64 + rowb - (g * 32 + l16)];
            b1 = bias_s[48 + rowb - (g * 32 + l16)];
          }
          float p0 = __builtin_amdgcn_exp2f(z[0][qi][r] + b0);
          float p1 = __builtin_amdgcn_exp2f(z[1][qi][r] + b1);
          psum[qi][r] += p0 + p1;
          union { float f; unsigned u; } a0, a1; a0.f = p0; a1.f = p1;
          unsigned pk = __builtin_amdgcn_perm(a1.u, a0.u, 0x07060302u);
          *(unsigned*)&pw[(quad * 4 + r) * 40 + 2 * l16] = pk;
        }
      }
      // ---- PV over this 32-key group ----
      bf16x8 pa0 = *(const bf16x8*)&P[wave][0][l16 * 40 + quad * 8];
      bf16x8 pa1 = *(const bf16x8*)&P[wave][1][l16 * 40 + quad * 8];
#pragma unroll
      for (int c = 0; c < 4; ++c) {
        bf16x8 vf = *(const bf16x8*)&Vs[g][(c * 16 + l16) * 40 + quad * 8];
        o[0][c] = mfma16(pa0, vf, o[0][c]);
        o[1][c] = mfma16(pa1, vf, o[1][c]);
      }
    }
    __syncthreads();
  }
  // ---- epilogue: row sums + normalize ----
#pragma unroll
  for (int qi = 0; qi < 2; ++qi)
#pragma unroll
    for (int off = 1; off < 16; off <<= 1)
#pragma unroll
      for (int r = 0; r < 4; ++r) psum[qi][r] += __shfl_xor(psum[qi][r], off);
#pragma unroll
  for (int qi = 0; qi < 2; ++qi)
#pragma unroll
    for (int r = 0; r < 4; ++r) {
      float inv = 1.f / psum[qi][r];
      int row = qw + qi * 16 + quad * 4 + r;
#pragma unroll
      for (int c = 0; c < 4; ++c)
        ctx[((size_t)(b * 2048 + row)) * 1024 + h * 64 + c * 16 + l16] = f2bf(o[qi][c][r] * inv);
    }
}

// ---------------- residual add + LayerNorm over D=1024 ----------------
template <int A_F32, int O_F32>
__global__ __launch_bounds__(256) void add_ln(const void* __restrict__ av, const u16* __restrict__ b,
                                              const float* __restrict__ gamma, const float* __restrict__ beta,
                                              void* __restrict__ ov) {
  const int row = blockIdx.x, t = threadIdx.x;
  const size_t base = (size_t)row * 1024 + t * 4;
  float x0, x1, x2, x3;
  if (A_F32) {
    float4 a4 = *(const float4*)((const float*)av + base);
    x0 = a4.x; x1 = a4.y; x2 = a4.z; x3 = a4.w;
  } else {
    ushort4 a4 = *(const ushort4*)((const u16*)av + base);
    x0 = bf2f(a4.x); x1 = bf2f(a4.y); x2 = bf2f(a4.z); x3 = bf2f(a4.w);
  }
  ushort4 b4 = *(const ushort4*)&b[base];
  x0 += bf2f(b4.x); x1 += bf2f(b4.y); x2 += bf2f(b4.z); x3 += bf2f(b4.w);
  float s = x0 + x1 + x2 + x3;
  float q = x0 * x0 + x1 * x1 + x2 * x2 + x3 * x3;
  for (int off = 32; off > 0; off >>= 1) { s += __shfl_down(s, off); q += __shfl_down(q, off); }
  __shared__ float sh_s[4], sh_q[4];
  if ((t & 63) == 0) { sh_s[t >> 6] = s; sh_q[t >> 6] = q; }
  __syncthreads();
  s = sh_s[0] + sh_s[1] + sh_s[2] + sh_s[3];
  q = sh_q[0] + sh_q[1] + sh_q[2] + sh_q[3];
  float mu = s * (1.f / 1024.f);
  float var = q * (1.f / 1024.f) - mu * mu;
  float rs = rsqrtf(var + 1e-5f);
  float4 g4 = *(const float4*)&gamma[t * 4];
  float4 be4 = *(const float4*)&beta[t * 4];
  float y0 = (x0 - mu) * rs * g4.x + be4.x;
  float y1 = (x1 - mu) * rs * g4.y + be4.y;
  float y2 = (x2 - mu) * rs * g4.z + be4.z;
  float y3 = (x3 - mu) * rs * g4.w + be4.w;
  if (O_F32) {
    float4 o4 = {y0, y1, y2, y3};
    *(float4*)((float*)ov + base) = o4;
  } else {
    ushort4 o4;
    o4.x = f2bf(y0); o4.y = f2bf(y1); o4.z = f2bf(y2); o4.w = f2bf(y3);
    *(ushort4*)((u16*)ov + base) = o4;
  }
}

extern "C" void kernel_launch(void* const* d_in, const int* in_sizes, int n_in,
                              void* d_out, int out_size, void* d_ws, size_t ws_size,
                              hipStream_t stream) {
  const float* x      = (const float*)d_in[0];
  const float* w_qkv  = (const float*)d_in[1];
  const float* w_out  = (const float*)d_in[2];
  const float* b_out  = (const float*)d_in[3];
  const float* btab   = (const float*)d_in[4];
  const float* gamma1 = (const float*)d_in[5];
  const float* beta1  = (const float*)d_in[6];
  const float* w_ff1  = (const float*)d_in[7];
  const float* b_ff1  = (const float*)d_in[8];
  const float* w_ff2  = (const float*)d_in[9];
  const float* b_ff2  = (const float*)d_in[10];
  const float* gamma2 = (const float*)d_in[11];
  const float* beta2  = (const float*)d_in[12];
  float* out = (float*)d_out;

  char* w = (char*)d_ws;
  auto alloc = [&](size_t elems) { u16* p = (u16*)w; w += elems * 2; return p; };
  u16* wqkvT = alloc(3072UL * 1024);
  u16* woutT = alloc(1024UL * 1024);
  u16* wff1T = alloc(4096UL * 1024);
  u16* wff2T = alloc(1024UL * 4096);
  u16* xb    = alloc(8192UL * 1024);   // x cast to bf16
  u16* qkv   = alloc(8192UL * 3072);   // dead after attn
  u16* vT2   = alloc(64UL * 64 * 2048);// dead after attn
  u16* ctx   = alloc(8192UL * 1024);   // dead after w_out gemm
  u16* x1    = alloc(8192UL * 1024);
  u16* attn  = qkv;                    // qkv region dead by then
  u16* h     = qkv;                    // h spans qkv+vT2, both dead
  u16* ffn   = ctx;                    // ctx dead after w_out gemm

  dim3 tb(32, 8);
  pack_bf16<<<8192, 256, 0, stream>>>(x, xb, 8192 * 1024 / 4);
  transpose_f2b<<<dim3(3072 / 32, 1024 / 32), tb, 0, stream>>>(w_qkv, wqkvT, 1024, 3072);
  transpose_f2b<<<dim3(1024 / 32, 1024 / 32), tb, 0, stream>>>(w_out, woutT, 1024, 1024);
  transpose_f2b<<<dim3(4096 / 32, 1024 / 32), tb, 0, stream>>>(w_ff1, wff1T, 1024, 4096);
  transpose_f2b<<<dim3(1024 / 32, 4096 / 32), tb, 0, stream>>>(w_ff2, wff2T, 4096, 1024);

  gemm_bt<0><<<dim3(24, 64), 256, 0, stream>>>(xb, wqkvT, nullptr, qkv, 8192, 3072, 1024);
  transpose_v<<<dim3(64, 2, 64), tb, 0, stream>>>(qkv, vT2);
  attn_kernel<<<1024, 256, 0, stream>>>(qkv, vT2, btab, ctx);
  gemm_bt<1><<<dim3(8, 64), 256, 0, stream>>>(ctx, woutT, b_out, attn, 8192, 1024, 1024);
  add_ln<1, 0><<<8192, 256, 0, stream>>>(x, attn, gamma1, beta1, x1);
  gemm_bt<2><<<dim3(32, 64), 256, 0, stream>>>(x1, wff1T, b_ff1, h, 8192, 4096, 1024);
  gemm_bt<1><<<dim3(8, 64), 256, 0, stream>>>(h, wff2T, b_ff2, ffn, 8192, 1024, 4096);
  add_ln<0, 1><<<8192, 256, 0, stream>>>(x1, ffn, gamma2, beta2, out);
}

// Round 6
// 560.644 us; speedup vs baseline: 2.1183x; 1.0853x over previous
//
#include <hip/hip_runtime.h>

typedef unsigned short u16;
typedef __bf16 bf16x8 __attribute__((ext_vector_type(8)));
typedef float f32x4 __attribute__((ext_vector_type(4)));
typedef unsigned short u16x8 __attribute__((ext_vector_type(8)));

typedef __attribute__((address_space(1))) const void gvoid_t;
typedef __attribute__((address_space(3))) void svoid_t;

__device__ __forceinline__ float bf2f(u16 u) {
  union { unsigned int i; float f; } v; v.i = ((unsigned int)u) << 16; return v.f;
}
__device__ __forceinline__ u16 f2bf(float f) {
  union { float f; unsigned int i; } v; v.f = f;
  unsigned int u = v.i;
  return (u16)((u + 0x7fffu + ((u >> 16) & 1u)) >> 16);
}
__device__ __forceinline__ void async_copy16(const u16* g, u16* l) {
  __builtin_amdgcn_global_load_lds((gvoid_t*)g, (svoid_t*)l, 16, 0, 0);
}
__device__ __forceinline__ f32x4 mfma16(bf16x8 a, bf16x8 b, f32x4 c) {
  return __builtin_amdgcn_mfma_f32_16x16x32_bf16(a, b, c, 0, 0, 0);
}
// tanh-form gelu via exp2+rcp (~10 VALU); max abs err vs exact-erf gelu ~3e-4,
// far below bf16 output quantization.
__device__ __forceinline__ float fast_gelu(float v) {
  float g = v * (0.7978845608028654f + 0.035677408136300125f * v * v);
  float t = __builtin_amdgcn_exp2f(g * 2.8853900817779268f);  // e^(2g)
  float th = 1.f - 2.f * __builtin_amdgcn_rcpf(t + 1.f);      // tanh(g)
  return 0.5f * v * (1.f + th);
}

// ---------------- fp32 -> bf16 elementwise pack ----------------
__global__ __launch_bounds__(256) void pack_bf16(const float* __restrict__ src, u16* __restrict__ dst, int n4) {
  int i = blockIdx.x * 256 + threadIdx.x;
  if (i >= n4) return;
  float4 v = *(const float4*)(src + (size_t)i * 4);
  ushort4 o;
  o.x = f2bf(v.x); o.y = f2bf(v.y); o.z = f2bf(v.z); o.w = f2bf(v.w);
  *(ushort4*)(dst + (size_t)i * 4) = o;
}

// ---------------- fp32 transpose+cast: src[R][C] f32 -> dst[C][R] bf16 ----------------
__global__ void transpose_f2b(const float* __restrict__ src, u16* __restrict__ dst, int R, int C) {
  __shared__ u16 t[32][33];
  const int c0 = blockIdx.x * 32, r0 = blockIdx.y * 32;
  const int tx = threadIdx.x, ty = threadIdx.y;
#pragma unroll
  for (int i = 0; i < 4; ++i) {
    int r = r0 + ty + i * 8;
    t[ty + i * 8][tx] = f2bf(src[(size_t)r * C + c0 + tx]);
  }
  __syncthreads();
#pragma unroll
  for (int i = 0; i < 4; ++i) {
    int c = c0 + ty + i * 8;
    dst[(size_t)c * R + r0 + tx] = t[tx][ty + i * 8];
  }
}

// ---------------- V transpose: qkv v-part (bf16) -> vT2[bh][kt32][d][32 perm] ----------------
__global__ void transpose_v(const u16* __restrict__ qkv, u16* __restrict__ vT2) {
  __shared__ u16 t[32][33];
  const int bh = blockIdx.z;
  const int b = bh >> 4, h = bh & 15;
  const int l0 = blockIdx.x * 32, d0 = blockIdx.y * 32;
  const int tx = threadIdx.x, ty = threadIdx.y;
#pragma unroll
  for (int i = 0; i < 4; ++i) {
    int l = l0 + ty + i * 8;
    t[ty + i * 8][tx] = qkv[(size_t)(b * 2048 + l) * 3072 + 2048 + h * 64 + d0 + tx];
  }
  __syncthreads();
  const int pos = 2 * (tx & 15) + (tx >> 4);
#pragma unroll
  for (int i = 0; i < 4; ++i) {
    int d = d0 + ty + i * 8;
    vT2[(size_t)bh * 131072 + (l0 >> 5) * 2048 + d * 32 + pos] = t[tx][ty + i * 8];
  }
}

// ---------------- GEMM: C[M,N](bf16) = A[M,K](bf16) @ Bt[N,K]^T (+bias f32)(+gelu) ----------------
// BK=64 via two 32-wide slabs: one barrier pair per 32 MFMAs/wave.
template <int EPI>
__global__ __launch_bounds__(256) void gemm_bt(const u16* __restrict__ A, const u16* __restrict__ Bt,
                                               const float* __restrict__ bias, u16* __restrict__ C,
                                               int M, int N, int K) {
  __shared__ __align__(16) u16 As[2][128 * 32];
  __shared__ __align__(16) u16 Bs[2][128 * 32];
  const int tid = threadIdx.x;
  const int wave = tid >> 6, lane = tid & 63;
  const int quad = lane >> 4, l16 = lane & 15;
  const int wm = wave >> 1, wn = wave & 1;
  const int m0 = blockIdx.y * 128, n0 = blockIdx.x * 128;
  const int srow = lane >> 2, scol = (lane & 3) * 8;
  f32x4 acc[4][4] = {};
  for (int k0 = 0; k0 < K; k0 += 64) {
#pragma unroll
    for (int s = 0; s < 2; ++s)
#pragma unroll
      for (int rr = 0; rr < 2; ++rr) {
        const int chunk = rr * 4 + wave;
        const int row = chunk * 16 + srow;
        async_copy16(&A[(size_t)(m0 + row) * K + k0 + s * 32 + scol], &As[s][chunk * 16 * 32]);
        async_copy16(&Bt[(size_t)(n0 + row) * K + k0 + s * 32 + scol], &Bs[s][chunk * 16 * 32]);
      }
    __syncthreads();
#pragma unroll
    for (int s = 0; s < 2; ++s) {
      bf16x8 af[4], bfv[4];
#pragma unroll
      for (int i = 0; i < 4; ++i)
        af[i] = *(const bf16x8*)&As[s][(wm * 64 + i * 16 + l16) * 32 + quad * 8];
#pragma unroll
      for (int j = 0; j < 4; ++j)
        bfv[j] = *(const bf16x8*)&Bs[s][(wn * 64 + j * 16 + l16) * 32 + quad * 8];
#pragma unroll
      for (int i = 0; i < 4; ++i)
#pragma unroll
        for (int j = 0; j < 4; ++j)
          acc[i][j] = mfma16(af[i], bfv[j], acc[i][j]);
    }
    __syncthreads();
  }
  // epilogue: row-pointer hoisted per (i,r); 4 offset stores per row
  float bv[4];
#pragma unroll
  for (int j = 0; j < 4; ++j)
    bv[j] = (EPI > 0) ? bias[n0 + wn * 64 + j * 16 + l16] : 0.f;
#pragma unroll
  for (int i = 0; i < 4; ++i)
#pragma unroll
    for (int r = 0; r < 4; ++r) {
      const int row = m0 + wm * 64 + i * 16 + quad * 4 + r;
      u16* cp = &C[(size_t)row * N + n0 + wn * 64 + l16];
#pragma unroll
      for (int j = 0; j < 4; ++j) {
        float v = acc[i][j][r] + bv[j];
        if (EPI == 2) v = fast_gelu(v);
        cp[j * 16] = f2bf(v);
      }
    }
}

// ---------------- flash attention, block-cooperative, 64-key iterations ----------------
__global__ __launch_bounds__(256, 4) void attn_kernel(const u16* __restrict__ qkv, const u16* __restrict__ vT2,
                                                      const float* __restrict__ btab, u16* __restrict__ ctx) {
  const int tid = threadIdx.x;
  const int wave = tid >> 6, lane = tid & 63;
  const int quad = lane >> 4, l16 = lane & 15;
  const int bh = blockIdx.x >> 4, qb = blockIdx.x & 15;
  const int b = bh >> 4, h = bh & 15;
  const int q0b = qb * 128;
  const int qw = q0b + wave * 32;
  const float LOG2E = 1.4426950408889634f;

  __shared__ __align__(16) u16 Ks[64 * 72];
  __shared__ __align__(16) u16 Vs[2][64 * 40];
  __shared__ __align__(16) float bias_s[192];
  __shared__ __align__(16) u16 P[4][2][16 * 40];

  bf16x8 qf[2][2];
#pragma unroll
  for (int qi = 0; qi < 2; ++qi)
#pragma unroll
    for (int kk = 0; kk < 2; ++kk) {
      u16x8 qv = *(const u16x8*)&qkv[((size_t)(b * 2048) + qw + qi * 16 + l16) * 3072 + h * 64 + kk * 32 + quad * 8];
      union { u16 s[8]; bf16x8 v; } u;
#pragma unroll
      for (int j = 0; j < 8; ++j) u.s[j] = f2bf(bf2f(qv[j]) * (0.125f * LOG2E));
      qf[qi][kk] = u.v;
    }

  f32x4 o[2][4] = {};
  float psum[2][4] = {};
  const float c_lo = btab[h] * LOG2E, c_hi = btab[1022 * 16 + h] * LOG2E;
  const int krow = tid >> 2, kc = tid & 3;
  const int rowb0 = wave * 32 + quad * 4;

  for (int kt = 0; kt < 32; ++kt) {
    const int kbase = kt * 64;
    const int dmin = kbase - q0b - 127, dmax = kbase - q0b + 63;
    const int mode = (dmax <= -511) ? 1 : (dmin >= 511 ? 2 : 0);
#pragma unroll
    for (int half = 0; half < 2; ++half) {
      const int chunk = kc + half * 4;
      u16x8 kv = *(const u16x8*)&qkv[((size_t)(b * 2048) + kbase + krow) * 3072 + 1024 + h * 64 + chunk * 8];
      *(u16x8*)&Ks[krow * 72 + chunk * 8] = kv;
    }
#pragma unroll
    for (int g = 0; g < 2; ++g) {
      u16x8 vv = *(const u16x8*)&vT2[(size_t)bh * 131072 + (2 * kt + g) * 2048 + tid * 8];
      *(u16x8*)&Vs[g][krow * 40 + kc * 8] = vv;
    }
    if (mode == 0 && tid < 192) {
      int idx = dmin + 191 - tid + 511;
      idx = min(max(idx, 0), 1022);
      bias_s[tid] = btab[idx * 16 + h] * LOG2E;
    }
    __syncthreads();
#pragma unroll
    for (int g = 0; g < 2; ++g) {
      f32x4 z[2][2];
#pragma unroll
      for (int t = 0; t < 2; ++t) {
        const u16* kr = &Ks[(g * 32 + t * 16 + l16) * 72 + quad * 8];
        bf16x8 kf0 = *(const bf16x8*)kr;
        bf16x8 kf1 = *(const bf16x8*)(kr + 32);
#pragma unroll
        for (int qi = 0; qi < 2; ++qi) {
          f32x4 zz = {0.f, 0.f, 0.f, 0.f};
          zz = mfma16(qf[qi][0], kf0, zz);
          zz = mfma16(qf[qi][1], kf1, zz);
          z[t][qi] = zz;
        }
      }
#pragma unroll
      for (int qi = 0; qi < 2; ++qi) {
        u16* pw = P[wave][qi];
#pragma unroll
        for (int r = 0; r < 4; ++r) {
          const int rowb = rowb0 + qi * 16 + r;
          float b0, b1;
          if (mode == 1) { b0 = c_lo; b1 = c_lo; }
          else if (mode == 2) { b0 = c_hi; b1 = c_hi; }
          else {
            b0 = bias_s[64 + rowb - (g * 32 + l16)];
            b1 = bias_s[48 + rowb - (g * 32 + l16)];
          }
          float p0 = __builtin_amdgcn_exp2f(z[0][qi][r] + b0);
          float p1 = __builtin_amdgcn_exp2f(z[1][qi][r] + b1);
          psum[qi][r] += p0 + p1;
          union { float f; unsigned u; } a0, a1; a0.f = p0; a1.f = p1;
          unsigned pk = __builtin_amdgcn_perm(a1.u, a0.u, 0x07060302u);
          *(unsigned*)&pw[(quad * 4 + r) * 40 + 2 * l16] = pk;
        }
      }
      bf16x8 pa0 = *(const bf16x8*)&P[wave][0][l16 * 40 + quad * 8];
      bf16x8 pa1 = *(const bf16x8*)&P[wave][1][l16 * 40 + quad * 8];
#pragma unroll
      for (int c = 0; c < 4; ++c) {
        bf16x8 vf = *(const bf16x8*)&Vs[g][(c * 16 + l16) * 40 + quad * 8];
        o[0][c] = mfma16(pa0, vf, o[0][c]);
        o[1][c] = mfma16(pa1, vf, o[1][c]);
      }
    }
    __syncthreads();
  }
#pragma unroll
  for (int qi = 0; qi < 2; ++qi)
#pragma unroll
    for (int off = 1; off < 16; off <<= 1)
#pragma unroll
      for (int r = 0; r < 4; ++r) psum[qi][r] += __shfl_xor(psum[qi][r], off);
#pragma unroll
  for (int qi = 0; qi < 2; ++qi)
#pragma unroll
    for (int r = 0; r < 4; ++r) {
      float inv = 1.f / psum[qi][r];
      int row = qw + qi * 16 + quad * 4 + r;
#pragma unroll
      for (int c = 0; c < 4; ++c)
        ctx[((size_t)(b * 2048 + row)) * 1024 + h * 64 + c * 16 + l16] = f2bf(o[qi][c][r] * inv);
    }
}

// ---------------- residual add + LayerNorm over D=1024 ----------------
template <int A_F32, int O_F32>
__global__ __launch_bounds__(256) void add_ln(const void* __restrict__ av, const u16* __restrict__ b,
                                              const float* __restrict__ gamma, const float* __restrict__ beta,
                                              void* __restrict__ ov) {
  const int row = blockIdx.x, t = threadIdx.x;
  const size_t base = (size_t)row * 1024 + t * 4;
  float x0, x1, x2, x3;
  if (A_F32) {
    float4 a4 = *(const float4*)((const float*)av + base);
    x0 = a4.x; x1 = a4.y; x2 = a4.z; x3 = a4.w;
  } else {
    ushort4 a4 = *(const ushort4*)((const u16*)av + base);
    x0 = bf2f(a4.x); x1 = bf2f(a4.y); x2 = bf2f(a4.z); x3 = bf2f(a4.w);
  }
  ushort4 b4 = *(const ushort4*)&b[base];
  x0 += bf2f(b4.x); x1 += bf2f(b4.y); x2 += bf2f(b4.z); x3 += bf2f(b4.w);
  float s = x0 + x1 + x2 + x3;
  float q = x0 * x0 + x1 * x1 + x2 * x2 + x3 * x3;
  for (int off = 32; off > 0; off >>= 1) { s += __shfl_down(s, off); q += __shfl_down(q, off); }
  __shared__ float sh_s[4], sh_q[4];
  if ((t & 63) == 0) { sh_s[t >> 6] = s; sh_q[t >> 6] = q; }
  __syncthreads();
  s = sh_s[0] + sh_s[1] + sh_s[2] + sh_s[3];
  q = sh_q[0] + sh_q[1] + sh_q[2] + sh_q[3];
  float mu = s * (1.f / 1024.f);
  float var = q * (1.f / 1024.f) - mu * mu;
  float rs = rsqrtf(var + 1e-5f);
  float4 g4 = *(const float4*)&gamma[t * 4];
  float4 be4 = *(const float4*)&beta[t * 4];
  float y0 = (x0 - mu) * rs * g4.x + be4.x;
  float y1 = (x1 - mu) * rs * g4.y + be4.y;
  float y2 = (x2 - mu) * rs * g4.z + be4.z;
  float y3 = (x3 - mu) * rs * g4.w + be4.w;
  if (O_F32) {
    float4 o4 = {y0, y1, y2, y3};
    *(float4*)((float*)ov + base) = o4;
  } else {
    ushort4 o4;
    o4.x = f2bf(y0); o4.y = f2bf(y1); o4.z = f2bf(y2); o4.w = f2bf(y3);
    *(ushort4*)((u16*)ov + base) = o4;
  }
}

extern "C" void kernel_launch(void* const* d_in, const int* in_sizes, int n_in,
                              void* d_out, int out_size, void* d_ws, size_t ws_size,
                              hipStream_t stream) {
  const float* x      = (const float*)d_in[0];
  const float* w_qkv  = (const float*)d_in[1];
  const float* w_out  = (const float*)d_in[2];
  const float* b_out  = (const float*)d_in[3];
  const float* btab   = (const float*)d_in[4];
  const float* gamma1 = (const float*)d_in[5];
  const float* beta1  = (const float*)d_in[6];
  const float* w_ff1  = (const float*)d_in[7];
  const float* b_ff1  = (const float*)d_in[8];
  const float* w_ff2  = (const float*)d_in[9];
  const float* b_ff2  = (const float*)d_in[10];
  const float* gamma2 = (const float*)d_in[11];
  const float* beta2  = (const float*)d_in[12];
  float* out = (float*)d_out;

  char* w = (char*)d_ws;
  auto alloc = [&](size_t elems) { u16* p = (u16*)w; w += elems * 2; return p; };
  u16* wqkvT = alloc(3072UL * 1024);
  u16* woutT = alloc(1024UL * 1024);
  u16* wff1T = alloc(4096UL * 1024);
  u16* wff2T = alloc(1024UL * 4096);
  u16* xb    = alloc(8192UL * 1024);
  u16* qkv   = alloc(8192UL * 3072);
  u16* vT2   = alloc(64UL * 64 * 2048);
  u16* ctx   = alloc(8192UL * 1024);
  u16* x1    = alloc(8192UL * 1024);
  u16* attn  = qkv;
  u16* h     = qkv;
  u16* ffn   = ctx;

  dim3 tb(32, 8);
  pack_bf16<<<8192, 256, 0, stream>>>(x, xb, 8192 * 1024 / 4);
  transpose_f2b<<<dim3(3072 / 32, 1024 / 32), tb, 0, stream>>>(w_qkv, wqkvT, 1024, 3072);
  transpose_f2b<<<dim3(1024 / 32, 1024 / 32), tb, 0, stream>>>(w_out, woutT, 1024, 1024);
  transpose_f2b<<<dim3(4096 / 32, 1024 / 32), tb, 0, stream>>>(w_ff1, wff1T, 1024, 4096);
  transpose_f2b<<<dim3(1024 / 32, 4096 / 32), tb, 0, stream>>>(w_ff2, wff2T, 4096, 1024);

  gemm_bt<0><<<dim3(24, 64), 256, 0, stream>>>(xb, wqkvT, nullptr, qkv, 8192, 3072, 1024);
  transpose_v<<<dim3(64, 2, 64), tb, 0, stream>>>(qkv, vT2);
  attn_kernel<<<1024, 256, 0, stream>>>(qkv, vT2, btab, ctx);
  gemm_bt<1><<<dim3(8, 64), 256, 0, stream>>>(ctx, woutT, b_out, attn, 8192, 1024, 1024);
  add_ln<1, 0><<<8192, 256, 0, stream>>>(x, attn, gamma1, beta1, x1);
  gemm_bt<2><<<dim3(32, 64), 256, 0, stream>>>(x1, wff1T, b_ff1, h, 8192, 4096, 1024);
  gemm_bt<1><<<dim3(8, 64), 256, 0, stream>>>(h, wff2T, b_ff2, ffn, 8192, 1024, 4096);
  add_ln<0, 1><<<8192, 256, 0, stream>>>(x1, ffn, gamma2, beta2, out);
}